// Round 3
// baseline (140.875 us; speedup 1.0000x reference)
//
#include <hip/hip_runtime.h>

typedef unsigned short u16;
typedef short short8 __attribute__((ext_vector_type(8)));
typedef float floatx4 __attribute__((ext_vector_type(4)));
typedef float floatx2 __attribute__((ext_vector_type(2)));
typedef unsigned int uintx4 __attribute__((ext_vector_type(4)));
typedef unsigned int uintx2 __attribute__((ext_vector_type(2)));
typedef u16 ushortx4 __attribute__((ext_vector_type(4)));

#define FEAT 1024
#define KNB  32

__device__ __forceinline__ u16 f2bf(float f) {
    unsigned u = __float_as_uint(f);
    u += 0x7fffu + ((u >> 16) & 1u);
    return (u16)(u >> 16);
}
__device__ __forceinline__ unsigned pack2bf(float a, float b) {
    return (unsigned)f2bf(a) | ((unsigned)f2bf(b) << 16);
}
__device__ __forceinline__ float softsign(float v) { return v / (1.f + fabsf(v)); }

union Frag { uintx4 q; unsigned d[4]; short8 v; };

// ---------------------------------------------------------------------------
// K2: layer-1 main kernel. grid=512 (node*8 + a-chunk of 128), block=256.
// Z[a,j] = sum_b sign(x_a*S_b + x_b*S_a) * Y[j][b],  Y = [x, nb0..nb31]
// epilogue: pws[n][chunk][j][o] = sum_{a in chunk} Z[a,j] * W1[o,a]
// ---------------------------------------------------------------------------
__global__ __launch_bounds__(256, 2) void k2_main(
    const float* __restrict__ xg, const float* __restrict__ nbg,
    const float* __restrict__ w1g, float* __restrict__ pws)
{
    __shared__ float sS[FEAT];      // 4 KB  S[b] = sum_k nb[n][k][b]  (f32)
    __shared__ float sX[FEAT];      // 4 KB  f32 copy of x (exact xb for sign-gen)
    __shared__ u16  sY[34 * 1024];  // 69.6 KB bf16: row0=x, 1..32=nb, 33=zeros; reused as Z

    const int t = threadIdx.x;
    const int n = blockIdx.x >> 3;
    const int chunk = blockIdx.x & 7;
    const int chunkbase = chunk * 128;
    const int w = t >> 6;       // wave 0..3
    const int l = t & 63;
    const int m = l & 15;       // MFMA row/col-in-tile
    const int g = l >> 4;       // quad (k-group)

    // ---- zero pad row 33 ----
    {
        ushortx4 z4 = {0, 0, 0, 0};
        *(ushortx4*)&sY[33 * 1024 + t * 4] = z4;
    }
    // ---- x row: f32 copy + bf16 row 0 (swizzle for row 0 is identity) ----
    {
        floatx4 xv = *(const floatx4*)(xg + (size_t)n * FEAT + t * 4);
        *(floatx4*)&sX[t * 4] = xv;
        ushortx4 xb4 = {f2bf(xv[0]), f2bf(xv[1]), f2bf(xv[2]), f2bf(xv[3])};
        *(ushortx4*)&sY[t * 4] = xb4;
    }
    // ---- single-pass: nb load -> S accumulate + bf16 stage (16B-chunk XOR swizzle) ----
    {
        const float* nbase = nbg + ((size_t)n * KNB) * FEAT + t * 4;
        floatx4 sacc = {0.f, 0.f, 0.f, 0.f};
        #pragma unroll 4
        for (int k = 0; k < KNB; ++k) {
            floatx4 v = *(const floatx4*)(nbase + (size_t)k * FEAT);
            sacc += v;
            int row = k + 1;
            int c16 = (t >> 1) ^ (row & 7);          // 16B chunk index 0..127
            ushortx4 p4 = {f2bf(v[0]), f2bf(v[1]), f2bf(v[2]), f2bf(v[3])};
            *(ushortx4*)&sY[row * 1024 + c16 * 8 + (t & 1) * 4] = p4;
        }
        *(floatx4*)&sS[t * 4] = sacc;
    }

    // per-lane A-side constants (a = chunkbase + w*32 + tile*16 + m)
    const float xa0 = xg[(size_t)n * FEAT + chunkbase + w * 32 + m];
    const float xa1 = xg[(size_t)n * FEAT + chunkbase + w * 32 + 16 + m];
    __syncthreads();
    const float Sa0 = sS[chunkbase + w * 32 + m];
    const float Sa1 = sS[chunkbase + w * 32 + 16 + m];

    const u16* b2base = (m == 0) ? &sY[32 * 1024] : &sY[33 * 1024];  // zeros if m!=0
    const int sw = (m & 7);

    floatx4 acc[2][3];
    #pragma unroll
    for (int i = 0; i < 2; ++i)
        #pragma unroll
        for (int j = 0; j < 3; ++j) { floatx4 z = {0.f, 0.f, 0.f, 0.f}; acc[i][j] = z; }

    const floatx2 vxa0 = {xa0, xa0}, vxa1 = {xa1, xa1};
    const floatx2 vSa0 = {Sa0, Sa0}, vSa1 = {Sa1, Sa1};

    #pragma unroll 2
    for (int s = 0; s < 32; ++s) {
        const int bloc = s * 32 + g * 8;   // this lane's 8 b-columns
        const int cidx = bloc >> 3;        // 16B chunk index

        floatx4 xq0 = *(const floatx4*)&sX[bloc];
        floatx4 xq1 = *(const floatx4*)&sX[bloc + 4];
        floatx4 sq0 = *(const floatx4*)&sS[bloc];
        floatx4 sq1 = *(const floatx4*)&sS[bloc + 4];

        Frag af0, af1;
        #pragma unroll
        for (int p = 0; p < 4; ++p) {
            floatx2 xbp = (p < 2) ? ((p == 0) ? (floatx2){xq0[0], xq0[1]} : (floatx2){xq0[2], xq0[3]})
                                  : ((p == 2) ? (floatx2){xq1[0], xq1[1]} : (floatx2){xq1[2], xq1[3]});
            floatx2 sbp = (p < 2) ? ((p == 0) ? (floatx2){sq0[0], sq0[1]} : (floatx2){sq0[2], sq0[3]})
                                  : ((p == 2) ? (floatx2){sq1[0], sq1[1]} : (floatx2){sq1[2], sq1[3]});
            floatx2 u0 = xbp * vSa0 + sbp * vxa0;   // v_pk_fma path
            floatx2 u1 = xbp * vSa1 + sbp * vxa1;
            uintx2 b0b = __builtin_bit_cast(uintx2, u0);
            uintx2 b1b = __builtin_bit_cast(uintx2, u1);
            af0.d[p] = 0x3F803F80u | (b0b.y & 0x80000000u) | ((b0b.x >> 16) & 0x8000u);
            af1.d[p] = 0x3F803F80u | (b1b.y & 0x80000000u) | ((b1b.x >> 16) & 0x8000u);
        }

        Frag b0, b1, b2;
        b0.q = *(const uintx4*)&sY[ m       * 1024 + ((cidx ^ sw) << 3)];
        b1.q = *(const uintx4*)&sY[(16 + m) * 1024 + ((cidx ^ sw) << 3)];
        b2.q = *(const uintx4*)&b2base[cidx << 3];   // row32 (sw=0) or zero row

        acc[0][0] = __builtin_amdgcn_mfma_f32_16x16x32_bf16(af0.v, b0.v, acc[0][0], 0, 0, 0);
        acc[0][1] = __builtin_amdgcn_mfma_f32_16x16x32_bf16(af0.v, b1.v, acc[0][1], 0, 0, 0);
        acc[0][2] = __builtin_amdgcn_mfma_f32_16x16x32_bf16(af0.v, b2.v, acc[0][2], 0, 0, 0);
        acc[1][0] = __builtin_amdgcn_mfma_f32_16x16x32_bf16(af1.v, b0.v, acc[1][0], 0, 0, 0);
        acc[1][1] = __builtin_amdgcn_mfma_f32_16x16x32_bf16(af1.v, b1.v, acc[1][1], 0, 0, 0);
        acc[1][2] = __builtin_amdgcn_mfma_f32_16x16x32_bf16(af1.v, b2.v, acc[1][2], 0, 0, 0);
    }
    __syncthreads();

    // ---- write Z (bf16) to LDS, layout [j 48][a 128] stride 136 ----
    u16* sZ = sY;
    #pragma unroll
    for (int ti = 0; ti < 2; ++ti)
        #pragma unroll
        for (int jt = 0; jt < 3; ++jt) {
            int j = jt * 16 + m;                  // C col = j
            int aloc = w * 32 + ti * 16 + g * 4;  // C rows = 4 consecutive a
            ushortx4 zz;
            zz.x = f2bf(acc[ti][jt][0]);
            zz.y = f2bf(acc[ti][jt][1]);
            zz.z = f2bf(acc[ti][jt][2]);
            zz.w = f2bf(acc[ti][jt][3]);
            *(ushortx4*)&sZ[j * 136 + aloc] = zz;
        }
    __syncthreads();

    // ---- epilogue: pws[n][chunk][j][o] = sum_{a in chunk} Z[a,j] * W1[o,a] ----
    floatx4 a2[3];
    #pragma unroll
    for (int j = 0; j < 3; ++j) { floatx4 z = {0.f, 0.f, 0.f, 0.f}; a2[j] = z; }
    #pragma unroll
    for (int kc = 0; kc < 4; ++kc) {
        const float* wsrc = w1g + (size_t)(w * 16 + m) * FEAT + chunkbase + kc * 32 + g * 8;
        floatx4 wf0 = *(const floatx4*)wsrc;
        floatx4 wf1 = *(const floatx4*)(wsrc + 4);
        Frag wb;
        wb.d[0] = pack2bf(wf0[0], wf0[1]);
        wb.d[1] = pack2bf(wf0[2], wf0[3]);
        wb.d[2] = pack2bf(wf1[0], wf1[1]);
        wb.d[3] = pack2bf(wf1[2], wf1[3]);
        #pragma unroll
        for (int jt = 0; jt < 3; ++jt) {
            Frag za;
            za.q = *(const uintx4*)&sZ[(jt * 16 + m) * 136 + kc * 32 + g * 8];
            a2[jt] = __builtin_amdgcn_mfma_f32_16x16x32_bf16(za.v, wb.v, a2[jt], 0, 0, 0);
        }
    }
    float* pbase = pws + (size_t)(n * 8 + chunk) * 33 * 64;
    #pragma unroll
    for (int jt = 0; jt < 3; ++jt)
        #pragma unroll
        for (int r = 0; r < 4; ++r) {
            int j = jt * 16 + g * 4 + r;
            if (j < 33) pbase[j * 64 + w * 16 + m] = a2[jt][r];
        }
}

// ---------------------------------------------------------------------------
// KB: per-node tail (64 blocks). Fuses: chunk-reduce, BN1-x (global stats,
// redundant per block), x1, nb BN (per n,c), S1, layer-2 adjacency, xa2, W2.
// ---------------------------------------------------------------------------
__global__ __launch_bounds__(256) void kB(
    const float* __restrict__ pws, const float* __restrict__ bn1w,
    const float* __restrict__ bn1b, const float* __restrict__ w2g,
    float* __restrict__ x22ws)
{
    __shared__ float sx2[64 * 64];           // [nn][o] all-node x2
    __shared__ float snb[32 * 64];           // [k][o] own-node nb
    __shared__ float sx1[64], sS1[64], sadj[4 * 16 * 16], sxa[64];
    __shared__ float ssc[4], sbi[4], ssc2[4], sbi2[4];
    const int t = threadIdx.x;
    const int n = blockIdx.x;

    #pragma unroll
    for (int r = 0; r < 16; ++r) {
        int idx = t + r * 256;               // nn*64 + o
        int nn = idx >> 6, o = idx & 63;
        float v = 0.f;
        #pragma unroll
        for (int c = 0; c < 8; ++c) v += pws[(size_t)((nn * 8 + c) * 33) * 64 + o];
        sx2[idx] = v;
    }
    #pragma unroll
    for (int r = 0; r < 8; ++r) {
        int idx = t + r * 256;               // k*64 + o
        int k = idx >> 6, o = idx & 63;
        float v = 0.f;
        #pragma unroll
        for (int c = 0; c < 8; ++c) v += pws[(size_t)((n * 8 + c) * 33 + 1 + k) * 64 + o];
        snb[idx] = v;
    }
    __syncthreads();
    {   // BN1 x-stats: wave cc reduces channel cc over (nn, f) = 1024 vals
        int cc = t >> 6, l2 = t & 63;
        float s = 0.f, s2 = 0.f;
        #pragma unroll
        for (int i = 0; i < 16; ++i) {
            int idx = l2 * 16 + i;
            int nn = idx >> 4, f = idx & 15;
            float v = sx2[nn * 64 + cc * 16 + f];
            s += v; s2 += v * v;
        }
        // BN1 nb-stats (own node): over (k, f) = 512 vals
        float s3 = 0.f, s4 = 0.f;
        #pragma unroll
        for (int i = 0; i < 8; ++i) {
            int idx = l2 * 8 + i;
            int k = idx >> 4, f = idx & 15;
            float v = snb[k * 64 + cc * 16 + f];
            s3 += v; s4 += v * v;
        }
        #pragma unroll
        for (int off = 32; off > 0; off >>= 1) {
            s  += __shfl_down(s, off);  s2 += __shfl_down(s2, off);
            s3 += __shfl_down(s3, off); s4 += __shfl_down(s4, off);
        }
        if (l2 == 0) {
            float wv = bn1w[cc], bv = bn1b[cc];
            float mean = s * (1.f / 1024.f);
            float var = s2 * (1.f / 1024.f) - mean * mean;
            float rs = rsqrtf(var + 1e-5f);
            ssc[cc] = rs * wv;
            sbi[cc] = bv - mean * rs * wv;
            float mean2 = s3 * (1.f / 512.f);
            float var2 = s4 * (1.f / 512.f) - mean2 * mean2;
            float rs2 = rsqrtf(var2 + 1e-5f);
            ssc2[cc] = rs2 * wv;
            sbi2[cc] = bv - mean2 * rs2 * wv;
        }
    }
    __syncthreads();
    if (t < 64) {
        int cc = t >> 4;
        sx1[t] = softsign(sx2[n * 64 + t] * ssc[cc] + sbi[cc]);
        float a = 0.f;
        for (int k = 0; k < KNB; ++k)
            a += softsign(snb[k * 64 + t] * ssc2[cc] + sbi2[cc]);
        sS1[t] = a;
    }
    __syncthreads();
    {   // exact layer-2 adjacency: one (a,b) pair per thread, channel-coupled denom
        int a = t >> 4, b = t & 15;
        float sc[4]; float den = 1e-7f;
        #pragma unroll
        for (int c = 0; c < 4; ++c) {
            float u = sx1[c * 16 + a] * sS1[c * 16 + b] + sx1[c * 16 + b] * sS1[c * 16 + a];
            float r = sqrtf(fmaxf(fabsf(u), 1e-8f));
            sc[c] = copysignf(r, u);
            den += r;
        }
        float inv = 1.f / den;
        #pragma unroll
        for (int c = 0; c < 4; ++c) sadj[(c * 16 + a) * 16 + b] = sc[c] * inv;
    }
    __syncthreads();
    if (t < 64) {                            // xa2[c][a] = sum_b adj2 * x1
        int cc = t >> 4;
        float a = 0.f;
        #pragma unroll
        for (int b = 0; b < 16; ++b) a += sadj[t * 16 + b] * sx1[cc * 16 + b];
        sxa[t] = a;
    }
    __syncthreads();
    if (t < 32) {                            // x2_2[o] = sum_{c,f} W2[o][c][f] * xa2
        float a = 0.f;
        #pragma unroll
        for (int cf = 0; cf < 64; ++cf) a += w2g[t * 64 + cf] * sxa[cf];
        x22ws[n * 32 + t] = a;
    }
}

// ---------------------------------------------------------------------------
// KC: BN2 (per o over nodes) + softsign + linear head -> f32 logits
// ---------------------------------------------------------------------------
__global__ __launch_bounds__(256) void kC(
    const float* __restrict__ x22ws, const float* __restrict__ bn2w,
    const float* __restrict__ bn2b, const float* __restrict__ linw,
    const float* __restrict__ linb, float* __restrict__ outg)
{
    __shared__ float sy[64 * 32];
    __shared__ float ssc[32], sbi[32];
    __shared__ float sx[64 * 32];
    const int t = threadIdx.x;
    #pragma unroll
    for (int r = 0; r < 8; ++r) sx[t + r * 256] = x22ws[t + r * 256];
    __syncthreads();
    if (t < 32) {
        float s = 0.f, s2 = 0.f;
        for (int nn = 0; nn < 64; ++nn) {
            float v = sx[nn * 32 + t];
            s += v; s2 += v * v;
        }
        float mean = s * (1.f / 64.f);
        float var = s2 * (1.f / 64.f) - mean * mean;
        float rs = rsqrtf(var + 1e-5f);
        float wv = bn2w[t], bv = bn2b[t];
        ssc[t] = rs * wv;
        sbi[t] = bv - mean * rs * wv;
    }
    __syncthreads();
    #pragma unroll
    for (int r = 0; r < 8; ++r) {
        int idx = t + r * 256;
        int o = idx & 31;
        sy[idx] = softsign(sx[idx] * ssc[o] + sbi[o]);
    }
    __syncthreads();
    for (int r = 0; r < 3; ++r) {
        int idx = t + r * 256;
        if (idx < 640) {
            int nn = idx / 10, cls = idx % 10;
            float a = linb[cls];
            #pragma unroll
            for (int o = 0; o < 32; ++o) a += sy[nn * 32 + o] * linw[cls * 32 + o];
            outg[idx] = a;
        }
    }
}

extern "C" void kernel_launch(void* const* d_in, const int* in_sizes, int n_in,
                              void* d_out, int out_size, void* d_ws, size_t ws_size,
                              hipStream_t stream) {
    (void)in_sizes; (void)n_in; (void)out_size; (void)ws_size;
    const float* xg   = (const float*)d_in[0];
    const float* nbg  = (const float*)d_in[1];
    const float* w1g  = (const float*)d_in[2];
    const float* w2g  = (const float*)d_in[3];
    const float* bn1w = (const float*)d_in[4];
    const float* bn1b = (const float*)d_in[5];
    const float* bn2w = (const float*)d_in[6];
    const float* bn2b = (const float*)d_in[7];
    const float* linw = (const float*)d_in[8];
    const float* linb = (const float*)d_in[9];

    float* pws   = (float*)d_ws;                       // [64][8][33][64] f32 partials
    float* x22ws = pws + (size_t)64 * 8 * 33 * 64;     // [64][32]
    float* outg  = (float*)d_out;

    k2_main<<<dim3(512), dim3(256), 0, stream>>>(xg, nbg, w1g, pws);
    kB<<<dim3(64), dim3(256), 0, stream>>>(pws, bn1w, bn1b, w2g, x22ws);
    kC<<<dim3(1), dim3(256), 0, stream>>>(x22ws, bn2w, bn2b, linw, linb, outg);
}

// Round 4
// 107.575 us; speedup vs baseline: 1.3096x; 1.3096x over previous
//
#include <hip/hip_runtime.h>

typedef unsigned short u16;
typedef short short8 __attribute__((ext_vector_type(8)));
typedef float floatx4 __attribute__((ext_vector_type(4)));
typedef float floatx2 __attribute__((ext_vector_type(2)));
typedef unsigned int uintx4 __attribute__((ext_vector_type(4)));
typedef unsigned int uintx2 __attribute__((ext_vector_type(2)));
typedef u16 ushortx4 __attribute__((ext_vector_type(4)));

#define FEAT 1024
#define KNB  32

__device__ __forceinline__ u16 f2bf(float f) {
    unsigned u = __float_as_uint(f);
    u += 0x7fffu + ((u >> 16) & 1u);
    return (u16)(u >> 16);
}
__device__ __forceinline__ unsigned pack2bf(float a, float b) {
    return (unsigned)f2bf(a) | ((unsigned)f2bf(b) << 16);
}
__device__ __forceinline__ float softsign(float v) { return v / (1.f + fabsf(v)); }

union Frag { uintx4 q; unsigned d[4]; short8 v; };

// ---------------------------------------------------------------------------
// K2: layer-1 main kernel. grid=512 (node*8 + a-chunk of 128), block=256.
// Z[a,j] = sum_b sign(x_a*S_b + x_b*S_a) * Y[j][b],  Y = [x, nb0..nb31]
// epilogue: pws[n][chunk][j][o] = sum_{a in chunk} Z[a,j] * W1[o,a]
// ---------------------------------------------------------------------------
__global__ __launch_bounds__(256, 2) void k2_main(
    const float* __restrict__ xg, const float* __restrict__ nbg,
    const float* __restrict__ w1g, float* __restrict__ pws)
{
    __shared__ float sS[FEAT];      // 4 KB  S[b] = sum_k nb[n][k][b]  (f32)
    __shared__ float sX[FEAT];      // 4 KB  f32 copy of x (exact xb for sign-gen)
    __shared__ u16  sY[34 * 1024];  // 69.6 KB bf16: row0=x, 1..32=nb, 33=zeros; reused as Z

    const int t = threadIdx.x;
    const int n = blockIdx.x >> 3;
    const int chunk = blockIdx.x & 7;
    const int chunkbase = chunk * 128;
    const int w = t >> 6;       // wave 0..3
    const int l = t & 63;
    const int m = l & 15;       // MFMA row/col-in-tile
    const int g = l >> 4;       // quad (k-group)

    // ---- zero pad row 33 ----
    {
        ushortx4 z4 = {0, 0, 0, 0};
        *(ushortx4*)&sY[33 * 1024 + t * 4] = z4;
    }
    // ---- x row: f32 copy + bf16 row 0 (swizzle for row 0 is identity) ----
    {
        floatx4 xv = *(const floatx4*)(xg + (size_t)n * FEAT + t * 4);
        *(floatx4*)&sX[t * 4] = xv;
        ushortx4 xb4 = {f2bf(xv[0]), f2bf(xv[1]), f2bf(xv[2]), f2bf(xv[3])};
        *(ushortx4*)&sY[t * 4] = xb4;
    }
    // ---- single-pass: nb load -> S accumulate + bf16 stage (16B-chunk XOR swizzle) ----
    {
        const float* nbase = nbg + ((size_t)n * KNB) * FEAT + t * 4;
        floatx4 sacc = {0.f, 0.f, 0.f, 0.f};
        #pragma unroll 4
        for (int k = 0; k < KNB; ++k) {
            floatx4 v = *(const floatx4*)(nbase + (size_t)k * FEAT);
            sacc += v;
            int row = k + 1;
            int c16 = (t >> 1) ^ (row & 7);          // 16B chunk index 0..127
            ushortx4 p4 = {f2bf(v[0]), f2bf(v[1]), f2bf(v[2]), f2bf(v[3])};
            *(ushortx4*)&sY[row * 1024 + c16 * 8 + (t & 1) * 4] = p4;
        }
        *(floatx4*)&sS[t * 4] = sacc;
    }

    // per-lane A-side constants (a = chunkbase + w*32 + tile*16 + m)
    const float xa0 = xg[(size_t)n * FEAT + chunkbase + w * 32 + m];
    const float xa1 = xg[(size_t)n * FEAT + chunkbase + w * 32 + 16 + m];
    __syncthreads();
    const float Sa0 = sS[chunkbase + w * 32 + m];
    const float Sa1 = sS[chunkbase + w * 32 + 16 + m];

    const u16* b2base = (m == 0) ? &sY[32 * 1024] : &sY[33 * 1024];  // zeros if m!=0
    const int sw = (m & 7);

    floatx4 acc[2][3];
    #pragma unroll
    for (int i = 0; i < 2; ++i)
        #pragma unroll
        for (int j = 0; j < 3; ++j) { floatx4 z = {0.f, 0.f, 0.f, 0.f}; acc[i][j] = z; }

    const floatx2 vxa0 = {xa0, xa0}, vxa1 = {xa1, xa1};
    const floatx2 vSa0 = {Sa0, Sa0}, vSa1 = {Sa1, Sa1};

    #pragma unroll 2
    for (int s = 0; s < 32; ++s) {
        const int bloc = s * 32 + g * 8;   // this lane's 8 b-columns
        const int cidx = bloc >> 3;        // 16B chunk index

        floatx4 xq0 = *(const floatx4*)&sX[bloc];
        floatx4 xq1 = *(const floatx4*)&sX[bloc + 4];
        floatx4 sq0 = *(const floatx4*)&sS[bloc];
        floatx4 sq1 = *(const floatx4*)&sS[bloc + 4];

        Frag af0, af1;
        #pragma unroll
        for (int p = 0; p < 4; ++p) {
            floatx2 xbp = (p < 2) ? ((p == 0) ? (floatx2){xq0[0], xq0[1]} : (floatx2){xq0[2], xq0[3]})
                                  : ((p == 2) ? (floatx2){xq1[0], xq1[1]} : (floatx2){xq1[2], xq1[3]});
            floatx2 sbp = (p < 2) ? ((p == 0) ? (floatx2){sq0[0], sq0[1]} : (floatx2){sq0[2], sq0[3]})
                                  : ((p == 2) ? (floatx2){sq1[0], sq1[1]} : (floatx2){sq1[2], sq1[3]});
            floatx2 u0 = xbp * vSa0 + sbp * vxa0;   // v_pk_fma path
            floatx2 u1 = xbp * vSa1 + sbp * vxa1;
            uintx2 b0b = __builtin_bit_cast(uintx2, u0);
            uintx2 b1b = __builtin_bit_cast(uintx2, u1);
            af0.d[p] = 0x3F803F80u | (b0b.y & 0x80000000u) | ((b0b.x >> 16) & 0x8000u);
            af1.d[p] = 0x3F803F80u | (b1b.y & 0x80000000u) | ((b1b.x >> 16) & 0x8000u);
        }

        Frag b0, b1, b2;
        b0.q = *(const uintx4*)&sY[ m       * 1024 + ((cidx ^ sw) << 3)];
        b1.q = *(const uintx4*)&sY[(16 + m) * 1024 + ((cidx ^ sw) << 3)];
        b2.q = *(const uintx4*)&b2base[cidx << 3];   // row32 (sw=0) or zero row

        acc[0][0] = __builtin_amdgcn_mfma_f32_16x16x32_bf16(af0.v, b0.v, acc[0][0], 0, 0, 0);
        acc[0][1] = __builtin_amdgcn_mfma_f32_16x16x32_bf16(af0.v, b1.v, acc[0][1], 0, 0, 0);
        acc[0][2] = __builtin_amdgcn_mfma_f32_16x16x32_bf16(af0.v, b2.v, acc[0][2], 0, 0, 0);
        acc[1][0] = __builtin_amdgcn_mfma_f32_16x16x32_bf16(af1.v, b0.v, acc[1][0], 0, 0, 0);
        acc[1][1] = __builtin_amdgcn_mfma_f32_16x16x32_bf16(af1.v, b1.v, acc[1][1], 0, 0, 0);
        acc[1][2] = __builtin_amdgcn_mfma_f32_16x16x32_bf16(af1.v, b2.v, acc[1][2], 0, 0, 0);
    }
    __syncthreads();

    // ---- write Z (bf16) to LDS, layout [j 48][a 128] stride 136 ----
    u16* sZ = sY;
    #pragma unroll
    for (int ti = 0; ti < 2; ++ti)
        #pragma unroll
        for (int jt = 0; jt < 3; ++jt) {
            int j = jt * 16 + m;                  // C col = j
            int aloc = w * 32 + ti * 16 + g * 4;  // C rows = 4 consecutive a
            ushortx4 zz;
            zz.x = f2bf(acc[ti][jt][0]);
            zz.y = f2bf(acc[ti][jt][1]);
            zz.z = f2bf(acc[ti][jt][2]);
            zz.w = f2bf(acc[ti][jt][3]);
            *(ushortx4*)&sZ[j * 136 + aloc] = zz;
        }
    __syncthreads();

    // ---- epilogue: pws[n][chunk][j][o] = sum_{a in chunk} Z[a,j] * W1[o,a] ----
    floatx4 a2[3];
    #pragma unroll
    for (int j = 0; j < 3; ++j) { floatx4 z = {0.f, 0.f, 0.f, 0.f}; a2[j] = z; }
    #pragma unroll
    for (int kc = 0; kc < 4; ++kc) {
        const float* wsrc = w1g + (size_t)(w * 16 + m) * FEAT + chunkbase + kc * 32 + g * 8;
        floatx4 wf0 = *(const floatx4*)wsrc;
        floatx4 wf1 = *(const floatx4*)(wsrc + 4);
        Frag wb;
        wb.d[0] = pack2bf(wf0[0], wf0[1]);
        wb.d[1] = pack2bf(wf0[2], wf0[3]);
        wb.d[2] = pack2bf(wf1[0], wf1[1]);
        wb.d[3] = pack2bf(wf1[2], wf1[3]);
        #pragma unroll
        for (int jt = 0; jt < 3; ++jt) {
            Frag za;
            za.q = *(const uintx4*)&sZ[(jt * 16 + m) * 136 + kc * 32 + g * 8];
            a2[jt] = __builtin_amdgcn_mfma_f32_16x16x32_bf16(za.v, wb.v, a2[jt], 0, 0, 0);
        }
    }
    float* pbase = pws + (size_t)(n * 8 + chunk) * 33 * 64;
    #pragma unroll
    for (int jt = 0; jt < 3; ++jt)
        #pragma unroll
        for (int r = 0; r < 4; ++r) {
            int j = jt * 16 + g * 4 + r;
            if (j < 33) pbase[j * 64 + w * 16 + m] = a2[jt][r];
        }
}

// ---------------------------------------------------------------------------
// KB: per-node tail (64 blocks). Chunk-reduce (float4, batched loads for ILP),
// BN1-x (global stats, redundant per block), x1, nb BN (per n,c), S1,
// layer-2 adjacency, xa2, W2.
// pws layout: [n][chunk][j][o] -> offset n*16896 + chunk*2112 + j*64 + o
// ---------------------------------------------------------------------------
__global__ __launch_bounds__(256, 1) void kB(
    const float* __restrict__ pws, const float* __restrict__ bn1w,
    const float* __restrict__ bn1b, const float* __restrict__ w2g,
    float* __restrict__ x22ws)
{
    __shared__ float sx2[64 * 64];           // [nn][o] all-node x2
    __shared__ float snb[32 * 64];           // [k][o] own-node nb
    __shared__ float sx1[64], sS1[64], sadj[4 * 16 * 16], sxa[64];
    __shared__ float ssc[4], sbi[4], ssc2[4], sbi2[4];
    const int t = threadIdx.x;
    const int n = blockIdx.x;

    // ---- x2 chunk-reduce: 1024 float4 slots (nn*16 + oc), 4 per thread ----
    #pragma unroll
    for (int r = 0; r < 4; ++r) {
        int slot = t + r * 256;
        int nn = slot >> 4, oc = slot & 15;
        const float* p = pws + (size_t)nn * 16896 + oc * 4;   // j = 0
        floatx4 tmp[8];
        #pragma unroll
        for (int c = 0; c < 8; ++c) tmp[c] = *(const floatx4*)(p + c * 2112);
        floatx4 s01 = tmp[0] + tmp[1], s23 = tmp[2] + tmp[3];
        floatx4 s45 = tmp[4] + tmp[5], s67 = tmp[6] + tmp[7];
        *(floatx4*)&sx2[slot * 4] = (s01 + s23) + (s45 + s67);
    }
    // ---- own-node nb chunk-reduce: 512 float4 slots (k*16 + oc), 2 per thread ----
    #pragma unroll
    for (int r = 0; r < 2; ++r) {
        int slot = t + r * 256;
        int k = slot >> 4, oc = slot & 15;
        const float* p = pws + (size_t)n * 16896 + (1 + k) * 64 + oc * 4;
        floatx4 tmp[8];
        #pragma unroll
        for (int c = 0; c < 8; ++c) tmp[c] = *(const floatx4*)(p + c * 2112);
        floatx4 s01 = tmp[0] + tmp[1], s23 = tmp[2] + tmp[3];
        floatx4 s45 = tmp[4] + tmp[5], s67 = tmp[6] + tmp[7];
        *(floatx4*)&snb[slot * 4] = (s01 + s23) + (s45 + s67);
    }
    __syncthreads();
    {   // BN1 x-stats: wave cc reduces channel cc over (nn, f) = 1024 vals
        int cc = t >> 6, l2 = t & 63;
        float s = 0.f, s2 = 0.f;
        #pragma unroll
        for (int i = 0; i < 16; ++i) {
            int idx = l2 * 16 + i;
            int nn = idx >> 4, f = idx & 15;
            float v = sx2[nn * 64 + cc * 16 + f];
            s += v; s2 += v * v;
        }
        // BN1 nb-stats (own node): over (k, f) = 512 vals
        float s3 = 0.f, s4 = 0.f;
        #pragma unroll
        for (int i = 0; i < 8; ++i) {
            int idx = l2 * 8 + i;
            int k = idx >> 4, f = idx & 15;
            float v = snb[k * 64 + cc * 16 + f];
            s3 += v; s4 += v * v;
        }
        #pragma unroll
        for (int off = 32; off > 0; off >>= 1) {
            s  += __shfl_down(s, off);  s2 += __shfl_down(s2, off);
            s3 += __shfl_down(s3, off); s4 += __shfl_down(s4, off);
        }
        if (l2 == 0) {
            float wv = bn1w[cc], bv = bn1b[cc];
            float mean = s * (1.f / 1024.f);
            float var = s2 * (1.f / 1024.f) - mean * mean;
            float rs = rsqrtf(var + 1e-5f);
            ssc[cc] = rs * wv;
            sbi[cc] = bv - mean * rs * wv;
            float mean2 = s3 * (1.f / 512.f);
            float var2 = s4 * (1.f / 512.f) - mean2 * mean2;
            float rs2 = rsqrtf(var2 + 1e-5f);
            ssc2[cc] = rs2 * wv;
            sbi2[cc] = bv - mean2 * rs2 * wv;
        }
    }
    __syncthreads();
    if (t < 64) {
        int cc = t >> 4;
        sx1[t] = softsign(sx2[n * 64 + t] * ssc[cc] + sbi[cc]);
        float a = 0.f;
        for (int k = 0; k < KNB; ++k)
            a += softsign(snb[k * 64 + t] * ssc2[cc] + sbi2[cc]);
        sS1[t] = a;
    }
    __syncthreads();
    {   // exact layer-2 adjacency: one (a,b) pair per thread, channel-coupled denom
        int a = t >> 4, b = t & 15;
        float sc[4]; float den = 1e-7f;
        #pragma unroll
        for (int c = 0; c < 4; ++c) {
            float u = sx1[c * 16 + a] * sS1[c * 16 + b] + sx1[c * 16 + b] * sS1[c * 16 + a];
            float r = sqrtf(fmaxf(fabsf(u), 1e-8f));
            sc[c] = copysignf(r, u);
            den += r;
        }
        float inv = 1.f / den;
        #pragma unroll
        for (int c = 0; c < 4; ++c) sadj[(c * 16 + a) * 16 + b] = sc[c] * inv;
    }
    __syncthreads();
    if (t < 64) {                            // xa2[c][a] = sum_b adj2 * x1
        int cc = t >> 4;
        float a = 0.f;
        #pragma unroll
        for (int b = 0; b < 16; ++b) a += sadj[t * 16 + b] * sx1[cc * 16 + b];
        sxa[t] = a;
    }
    __syncthreads();
    if (t < 32) {                            // x2_2[o] = sum_{c,f} W2[o][c][f] * xa2
        float a = 0.f;
        #pragma unroll
        for (int cf = 0; cf < 64; ++cf) a += w2g[t * 64 + cf] * sxa[cf];
        x22ws[n * 32 + t] = a;
    }
}

// ---------------------------------------------------------------------------
// KC: BN2 (per o over nodes) + softsign + linear head -> f32 logits
// ---------------------------------------------------------------------------
__global__ __launch_bounds__(256) void kC(
    const float* __restrict__ x22ws, const float* __restrict__ bn2w,
    const float* __restrict__ bn2b, const float* __restrict__ linw,
    const float* __restrict__ linb, float* __restrict__ outg)
{
    __shared__ float sy[64 * 32];
    __shared__ float ssc[32], sbi[32];
    __shared__ float sx[64 * 32];
    const int t = threadIdx.x;
    #pragma unroll
    for (int r = 0; r < 8; ++r) sx[t + r * 256] = x22ws[t + r * 256];
    __syncthreads();
    if (t < 32) {
        float s = 0.f, s2 = 0.f;
        for (int nn = 0; nn < 64; ++nn) {
            float v = sx[nn * 32 + t];
            s += v; s2 += v * v;
        }
        float mean = s * (1.f / 64.f);
        float var = s2 * (1.f / 64.f) - mean * mean;
        float rs = rsqrtf(var + 1e-5f);
        float wv = bn2w[t], bv = bn2b[t];
        ssc[t] = rs * wv;
        sbi[t] = bv - mean * rs * wv;
    }
    __syncthreads();
    #pragma unroll
    for (int r = 0; r < 8; ++r) {
        int idx = t + r * 256;
        int o = idx & 31;
        sy[idx] = softsign(sx[idx] * ssc[o] + sbi[o]);
    }
    __syncthreads();
    for (int r = 0; r < 3; ++r) {
        int idx = t + r * 256;
        if (idx < 640) {
            int nn = idx / 10, cls = idx % 10;
            float a = linb[cls];
            #pragma unroll
            for (int o = 0; o < 32; ++o) a += sy[nn * 32 + o] * linw[cls * 32 + o];
            outg[idx] = a;
        }
    }
}

extern "C" void kernel_launch(void* const* d_in, const int* in_sizes, int n_in,
                              void* d_out, int out_size, void* d_ws, size_t ws_size,
                              hipStream_t stream) {
    (void)in_sizes; (void)n_in; (void)out_size; (void)ws_size;
    const float* xg   = (const float*)d_in[0];
    const float* nbg  = (const float*)d_in[1];
    const float* w1g  = (const float*)d_in[2];
    const float* w2g  = (const float*)d_in[3];
    const float* bn1w = (const float*)d_in[4];
    const float* bn1b = (const float*)d_in[5];
    const float* bn2w = (const float*)d_in[6];
    const float* bn2b = (const float*)d_in[7];
    const float* linw = (const float*)d_in[8];
    const float* linb = (const float*)d_in[9];

    float* pws   = (float*)d_ws;                       // [64][8][33][64] f32 partials
    float* x22ws = pws + (size_t)64 * 8 * 33 * 64;     // [64][32]
    float* outg  = (float*)d_out;

    k2_main<<<dim3(512), dim3(256), 0, stream>>>(xg, nbg, w1g, pws);
    kB<<<dim3(64), dim3(256), 0, stream>>>(pws, bn1w, bn1b, w2g, x22ws);
    kC<<<dim3(1), dim3(256), 0, stream>>>(x22ws, bn2w, bn2b, linw, linb, outg);
}